// Round 1
// baseline (1298.522 us; speedup 1.0000x reference)
//
#include <hip/hip_runtime.h>
#include <hip/hip_bf16.h>
#include <math.h>

#define N     8192
#define NB    8
#define HID   128
#define RANK  5
#define DT    0.1f
#define JC    2048   // j-chunk staged in LDS for the step kernel

__device__ __forceinline__ float softplusf(float x) {
    return fmaxf(x, 0.0f) + log1pf(expf(-fabsf(x)));
}

// ---------------- MLP layer 1 (x @ W[N,HID]) : partial sums over k-chunks ----------------
// grid 64, block 128. Block kb covers k in [kb*128, kb*128+128). partial[kb][b][j]
__global__ void mlp1_partial(const float* __restrict__ in0,
                             const float* __restrict__ in1,   // added when add_two=1
                             const float* __restrict__ W,     // [N][HID]
                             float* __restrict__ partial,
                             int add_two)
{
    __shared__ float xs[NB][128];
    const int kb = blockIdx.x;
    const int j  = threadIdx.x;
    for (int t = threadIdx.x; t < NB * 128; t += 128) {
        int b = t >> 7, kk = t & 127;
        int k = kb * 128 + kk;
        float v = in0[(size_t)b * N + k];
        if (add_two) v += in1[(size_t)b * N + k];
        xs[b][kk] = v;
    }
    __syncthreads();
    float acc[NB];
#pragma unroll
    for (int b = 0; b < NB; ++b) acc[b] = 0.f;
    for (int kk = 0; kk < 128; ++kk) {
        float w = W[(size_t)(kb * 128 + kk) * HID + j];
#pragma unroll
        for (int b = 0; b < NB; ++b) acc[b] = fmaf(xs[b][kk], w, acc[b]);
    }
#pragma unroll
    for (int b = 0; b < NB; ++b) partial[(size_t)(kb * NB + b) * HID + j] = acc[b];
}

// grid 8 (one per batch), block 128. h[b][j] = relu(sum_kb partial + bias[j])
__global__ void mlp1_reduce(const float* __restrict__ partial,
                            const float* __restrict__ bias,
                            float* __restrict__ h)
{
    int b = blockIdx.x, j = threadIdx.x;
    float s = bias[j];
    for (int kb = 0; kb < 64; ++kb) s += partial[(size_t)(kb * NB + b) * HID + j];
    h[b * HID + j] = fmaxf(s, 0.f);
}

// ---------------- MLP layer 2 for the gate: gate=sigmoid(h@W2+b2); us=g*x0; uf=(1-g)*x0 ----
// grid 64, block 128 : i = blockIdx*128 + tid
__global__ void mlp2_gate(const float* __restrict__ h, const float* __restrict__ W2,
                          const float* __restrict__ b2, const float* __restrict__ x0,
                          float* __restrict__ us, float* __restrict__ uf)
{
    __shared__ float hs[NB][HID];
    for (int t = threadIdx.x; t < NB * HID; t += 128) hs[t >> 7][t & 127] = h[t];
    __syncthreads();
    int i = blockIdx.x * 128 + threadIdx.x;
    float bb = b2[i];
    float acc[NB];
#pragma unroll
    for (int b = 0; b < NB; ++b) acc[b] = bb;
    for (int jj = 0; jj < HID; ++jj) {
        float w = W2[(size_t)jj * N + i];
#pragma unroll
        for (int b = 0; b < NB; ++b) acc[b] = fmaf(hs[b][jj], w, acc[b]);
    }
#pragma unroll
    for (int b = 0; b < NB; ++b) {
        float g = 1.f / (1.f + expf(-acc[b]));
        float x = x0[(size_t)b * N + i];
        us[(size_t)b * N + i] = g * x;
        uf[(size_t)b * N + i] = (1.f - g) * x;
    }
}

// ---------------- MLP layer 2 for the decoder: out = softplus(h@D2+db2) ----------------
__global__ void mlp2_dec(const float* __restrict__ h, const float* __restrict__ W2,
                         const float* __restrict__ b2, float* __restrict__ out)
{
    __shared__ float hs[NB][HID];
    for (int t = threadIdx.x; t < NB * HID; t += 128) hs[t >> 7][t & 127] = h[t];
    __syncthreads();
    int i = blockIdx.x * 128 + threadIdx.x;
    float bb = b2[i];
    float acc[NB];
#pragma unroll
    for (int b = 0; b < NB; ++b) acc[b] = bb;
    for (int jj = 0; jj < HID; ++jj) {
        float w = W2[(size_t)jj * N + i];
#pragma unroll
        for (int b = 0; b < NB; ++b) acc[b] = fmaf(hs[b][jj], w, acc[b]);
    }
#pragma unroll
    for (int b = 0; b < NB; ++b) out[(size_t)b * N + i] = softplusf(acc[b]);
}

// ---------------- rank-5 projections: ps = uf@Ms_B, pf = us@Mf_B ----------------
// grid 80, block 256. bid: m = bid/40 (0:ps from uf, 1:pf from us), rem -> (b, r)
__global__ void pk(const float* __restrict__ us, const float* __restrict__ uf,
                   const float* __restrict__ MsB, const float* __restrict__ MfB,
                   float* __restrict__ p)   // [2][NB][RANK]
{
    __shared__ float red[256];
    const int m = blockIdx.x / 40, rem = blockIdx.x % 40;
    const int b = rem / RANK, r = rem % RANK;
    const float* u  = m ? us : uf;
    const float* Bm = m ? MfB : MsB;
    float s = 0.f;
    for (int j = threadIdx.x; j < N; j += 256)
        s += u[(size_t)b * N + j] * Bm[(size_t)j * RANK + r];
    red[threadIdx.x] = s;
    __syncthreads();
    for (int w = 128; w > 0; w >>= 1) {
        if (threadIdx.x < w) red[threadIdx.x] += red[threadIdx.x + w];
        __syncthreads();
    }
    if (threadIdx.x == 0) p[m * 40 + rem] = red[0];
}

// ---------------- the big step kernel: Y = u @ L^T rows + fused update ----------------
// grid 512 (first 256: s-matrix rows, last 256: f-matrix rows), block 256 (4 waves).
// Block owns 32 rows; wave owns 8 rows; lanes split j (float4). u staged in LDS by chunks.
__global__ __launch_bounds__(256, 2) void step_kernel(
    const float* __restrict__ us_in, const float* __restrict__ uf_in,
    float* __restrict__ us_out, float* __restrict__ uf_out,
    const float* __restrict__ Ls, const float* __restrict__ Lf,
    const float* __restrict__ MsA, const float* __restrict__ MfA,
    const float* __restrict__ p,
    const float* __restrict__ rcs, const float* __restrict__ rcf,
    const float* __restrict__ rls, const float* __restrict__ rlf)
{
    __shared__ float u_lds[NB][JC];   // 64 KB (reused as reduction scratch)
    const int bid  = blockIdx.x;
    const bool isf = bid >= 256;
    const int row0 = (bid & 255) * 32;
    const int wave = threadIdx.x >> 6;
    const int lane = threadIdx.x & 63;
    const float* __restrict__ u_in = isf ? uf_in : us_in;
    const float* __restrict__ L    = isf ? Lf : Ls;
    const int rowbase = row0 + wave * 8;

    float acc[8][NB];
#pragma unroll
    for (int r = 0; r < 8; ++r)
#pragma unroll
        for (int b = 0; b < NB; ++b) acc[r][b] = 0.f;

    for (int chunk = 0; chunk < N / JC; ++chunk) {
        const int jbase = chunk * JC;
        __syncthreads();   // previous-iteration readers done before overwrite
        for (int t = threadIdx.x; t < NB * JC / 4; t += 256) {
            int flat = t * 4;
            int b = flat / JC, jj = flat % JC;
            *(float4*)&u_lds[b][jj] = *(const float4*)&u_in[(size_t)b * N + jbase + jj];
        }
        __syncthreads();
        for (int jit = 0; jit < JC / 256; ++jit) {
            const int jl = jit * 256 + lane * 4;
            float4 uv[NB];
#pragma unroll
            for (int b = 0; b < NB; ++b) uv[b] = *(const float4*)&u_lds[b][jl];
#pragma unroll
            for (int r = 0; r < 8; ++r) {
                const float4 a = *(const float4*)&L[(size_t)(rowbase + r) * N + jbase + jl];
#pragma unroll
                for (int b = 0; b < NB; ++b) {
                    acc[r][b] = fmaf(a.x, uv[b].x, acc[r][b]);
                    acc[r][b] = fmaf(a.y, uv[b].y, acc[r][b]);
                    acc[r][b] = fmaf(a.z, uv[b].z, acc[r][b]);
                    acc[r][b] = fmaf(a.w, uv[b].w, acc[r][b]);
                }
            }
        }
    }

    // cross-lane reduction through LDS (64KB == 4 waves * 64 vals * 64 lanes * 4B)
    __syncthreads();
    float* red = &u_lds[0][0];
#pragma unroll
    for (int r = 0; r < 8; ++r)
#pragma unroll
        for (int b = 0; b < NB; ++b)
            red[(size_t)(wave * 64 + r * 8 + b) * 64 + lane] = acc[r][b];
    __syncthreads();

    {
        const int tid = threadIdx.x;        // value index == tid: w=tid>>6, v=tid&63
        const int w = tid >> 6, v = tid & 63;
        const int r = v >> 3, b = v & 7;
        const float* base = red + (size_t)tid * 64;
        float s = 0.f;
#pragma unroll
        for (int i = 0; i < 64; ++i) s += base[(v + i) & 63];   // staggered: 2-way max

        const int row = row0 + w * 8 + r;
        if (!isf) {
            float c = softplusf(rcs[0]) + 1e-4f;
            float l = softplusf(rls[0]) + 1e-4f;
            float lr = 0.f;
#pragma unroll
            for (int rr = 0; rr < RANK; ++rr)
                lr = fmaf(p[b * RANK + rr], MsA[(size_t)row * RANK + rr], lr);
            float v0 = us_in[(size_t)b * N + row];
            float du = fmaf(-c, s, l * lr);
            us_out[(size_t)b * N + row] = fmaxf(fmaf(DT, du, v0), 0.f);
        } else {
            float c = softplusf(rcf[0]) + 1e-4f;
            float l = softplusf(rlf[0]) + 1e-4f;
            float lr = 0.f;
#pragma unroll
            for (int rr = 0; rr < RANK; ++rr)
                lr = fmaf(p[40 + b * RANK + rr], MfA[(size_t)row * RANK + rr], lr);
            float v0 = uf_in[(size_t)b * N + row];
            float du = fmaf(-c, s, l * lr);
            uf_out[(size_t)b * N + row] = fmaxf(fmaf(DT, du, v0), 0.f);
        }
    }
}

extern "C" void kernel_launch(void* const* d_in, const int* in_sizes, int n_in,
                              void* d_out, int out_size, void* d_ws, size_t ws_size,
                              hipStream_t stream) {
    const float* x0  = (const float*)d_in[0];
    const float* Ls  = (const float*)d_in[1];
    const float* Lf  = (const float*)d_in[2];
    const float* W1  = (const float*)d_in[3];
    const float* b1  = (const float*)d_in[4];
    const float* W2  = (const float*)d_in[5];
    const float* b2  = (const float*)d_in[6];
    const float* MsA = (const float*)d_in[7];
    const float* MsB = (const float*)d_in[8];
    const float* MfA = (const float*)d_in[9];
    const float* MfB = (const float*)d_in[10];
    const float* rcs = (const float*)d_in[11];
    const float* rcf = (const float*)d_in[12];
    const float* rls = (const float*)d_in[13];
    const float* rlf = (const float*)d_in[14];
    const float* D1  = (const float*)d_in[15];
    const float* db1 = (const float*)d_in[16];
    const float* D2  = (const float*)d_in[17];
    const float* db2 = (const float*)d_in[18];

    float* out = (float*)d_out;
    float* ws  = (float*)d_ws;

    float* usA = ws;
    float* ufA = ws + 65536;
    float* usB = ws + 131072;
    float* ufB = ws + 196608;
    float* p   = ws + 262144;   // 80 floats
    float* h   = ws + 262400;   // 1024 floats
    float* prt = ws + 263424;   // 64*8*128 = 65536 floats

    // gate MLP -> us0, uf0
    mlp1_partial<<<64, 128, 0, stream>>>(x0, x0, W1, prt, 0);
    mlp1_reduce<<<8, 128, 0, stream>>>(prt, b1, h);
    mlp2_gate<<<64, 128, 0, stream>>>(h, W2, b2, x0, usA, ufA);

    float *ui = usA, *vi = ufA, *uo = usB, *vo = ufB;
    for (int t = 0; t < 10; ++t) {
        pk<<<80, 256, 0, stream>>>(ui, vi, MsB, MfB, p);
        float* uso = (t == 9) ? (out + 65536)  : uo;
        float* ufo = (t == 9) ? (out + 131072) : vo;
        step_kernel<<<512, 256, 0, stream>>>(ui, vi, uso, ufo, Ls, Lf, MsA, MfA, p,
                                             rcs, rcf, rls, rlf);
        float* tmp;
        tmp = ui; ui = uo; uo = tmp;
        tmp = vi; vi = vo; vo = tmp;
    }

    // decoder MLP on latent = us + uf (read from d_out where step 9 wrote them)
    mlp1_partial<<<64, 128, 0, stream>>>(out + 65536, out + 131072, D1, prt, 1);
    mlp1_reduce<<<8, 128, 0, stream>>>(prt, db1, h);
    mlp2_dec<<<64, 128, 0, stream>>>(h, D2, db2, out);
}